// Round 1
// baseline (143.013 us; speedup 1.0000x reference)
//
#include <hip/hip_runtime.h>
#include <math.h>

#define CAP   32768
#define NB    32
#define ROWS  64
#define NBLK  (CAP / ROWS)   // 512
#define TOPK  16
#define CEPS  1e-8f

#define PITCH 68              // LDS row pitch (floats); 16B-aligned rows
#define CHUNK 1024
#define NCHUNK (CAP / CHUNK)  // 32

// ws layout (floats)
#define WS_FINAL 0            // [32][32768] final scores

__global__ __launch_bounds__(256, 2) void score_kernel(
    const float* __restrict__ qc,     // [32][64]
    const float* __restrict__ qctx,   // [32][64]
    const float* __restrict__ mcont,  // [CAP][64]
    const float* __restrict__ mctx,   // [CAP][64]
    const float* __restrict__ fresh,  // [CAP]
    const float* __restrict__ W1,     // [128][64]
    const float* __restrict__ b1,     // [64]
    const float* __restrict__ W2,     // [64]
    const float* __restrict__ b2,     // [1]
    float* __restrict__ ws)
{
    __shared__ float s_mc[ROWS * PITCH];   // mc tile; after phase A: m_part^T [j][c]
    __shared__ float s_qp[NB * PITCH];
    __shared__ float s_qn[NB * PITCH];
    __shared__ float s_base[ROWS];         // 0.2 * freshness
    __shared__ float s_inv[ROWS];          // 0.3 / max(||mctx||, eps)

    const int tid = threadIdx.x;
    const int C0 = blockIdx.x * ROWS;

    // ---- staging: mc tile (coalesced), mctx norms ----
    const float4* g_mc = (const float4*)(mcont + (size_t)C0 * 64);
    #pragma unroll
    for (int t = tid; t < ROWS * 16; t += 256) {
        int r = t >> 4, c4 = t & 15;
        *(float4*)&s_mc[r * PITCH + c4 * 4] = g_mc[t];
    }
    {   // mctx norms: thread t -> row r=t>>2, quarter q=t&3 (coalesced b128 loads)
        const int r = tid >> 2, q = tid & 3;
        const float* xr = mctx + (size_t)(C0 + r) * 64 + q * 16;
        float ss = 0.f;
        #pragma unroll
        for (int i = 0; i < 4; ++i) {
            float4 x = *(const float4*)&xr[i * 4];
            ss = fmaf(x.x, x.x, ss); ss = fmaf(x.y, x.y, ss);
            ss = fmaf(x.z, x.z, ss); ss = fmaf(x.w, x.w, ss);
        }
        ss += __shfl_xor(ss, 1, 64);
        ss += __shfl_xor(ss, 2, 64);
        if (q == 0) {
            s_inv[r]  = 0.3f / fmaxf(sqrtf(ss), CEPS);
            s_base[r] = 0.2f * fresh[C0 + r];
        }
    }

    // ---- fused prep: qp = qc@W1lo + b1 and qn = normalize(qctx), in-block.
    //      Bit-identical arithmetic to the old prep_kernel (same fma order,
    //      same shfl-tree, same divide) so top-k ordering cannot change.
    //      Wave wv handles b = wv*8 .. wv*8+7; W1lo column j held in 64 VGPRs.
    {
        const int lane = tid & 63;
        const int wv = tid >> 6;           // 0..3
        float w1c[64];
        #pragma unroll
        for (int i = 0; i < 64; ++i) w1c[i] = W1[i * 64 + lane];   // coalesced, L2-hot
        const float b1v = b1[lane];
        #pragma unroll
        for (int bb = 0; bb < 8; ++bb) {
            const int b = wv * 8 + bb;
            const float4* qc4 = (const float4*)(qc + b * 64);      // wave-uniform bcast
            float a0 = b1v, a1 = 0.f, a2 = 0.f, a3 = 0.f;
            #pragma unroll
            for (int i4 = 0; i4 < 16; ++i4) {
                float4 q4 = qc4[i4];
                a0 = fmaf(q4.x, w1c[4 * i4 + 0], a0);
                a1 = fmaf(q4.y, w1c[4 * i4 + 1], a1);
                a2 = fmaf(q4.z, w1c[4 * i4 + 2], a2);
                a3 = fmaf(q4.w, w1c[4 * i4 + 3], a3);
            }
            s_qp[b * PITCH + lane] = (a0 + a1) + (a2 + a3);

            float x = qctx[b * 64 + lane];
            float ss = x * x;
            ss += __shfl_xor(ss, 1,  64);
            ss += __shfl_xor(ss, 2,  64);
            ss += __shfl_xor(ss, 4,  64);
            ss += __shfl_xor(ss, 8,  64);
            ss += __shfl_xor(ss, 16, 64);
            ss += __shfl_xor(ss, 32, 64);
            s_qn[b * PITCH + lane] = x / fmaxf(sqrtf(ss), CEPS);
        }
    }
    __syncthreads();

    // ---- phase A: m_part = MC @ W1lo, 4c x 4j register tile.
    //      mc rows from LDS (stride 68 -> 2-way, free); W1 from global (broadcast, L1-hot)
    const int c_lo = tid & 15;
    const int j0 = (tid >> 4) * 4;
    {
        float acc[4][4] = {{0.f}};
        #pragma unroll 4
        for (int i4 = 0; i4 < 16; ++i4) {
            float4 w0 = *(const float4*)&W1[(64 + i4 * 4 + 0) * 64 + j0];
            float4 w1r = *(const float4*)&W1[(64 + i4 * 4 + 1) * 64 + j0];
            float4 w2r = *(const float4*)&W1[(64 + i4 * 4 + 2) * 64 + j0];
            float4 w3r = *(const float4*)&W1[(64 + i4 * 4 + 3) * 64 + j0];
            #pragma unroll
            for (int ci = 0; ci < 4; ++ci) {
                float4 m = *(const float4*)&s_mc[(c_lo + 16 * ci) * PITCH + i4 * 4];
                acc[ci][0] = fmaf(m.x, w0.x, acc[ci][0]);
                acc[ci][1] = fmaf(m.x, w0.y, acc[ci][1]);
                acc[ci][2] = fmaf(m.x, w0.z, acc[ci][2]);
                acc[ci][3] = fmaf(m.x, w0.w, acc[ci][3]);
                acc[ci][0] = fmaf(m.y, w1r.x, acc[ci][0]);
                acc[ci][1] = fmaf(m.y, w1r.y, acc[ci][1]);
                acc[ci][2] = fmaf(m.y, w1r.z, acc[ci][2]);
                acc[ci][3] = fmaf(m.y, w1r.w, acc[ci][3]);
                acc[ci][0] = fmaf(m.z, w2r.x, acc[ci][0]);
                acc[ci][1] = fmaf(m.z, w2r.y, acc[ci][1]);
                acc[ci][2] = fmaf(m.z, w2r.z, acc[ci][2]);
                acc[ci][3] = fmaf(m.z, w2r.w, acc[ci][3]);
                acc[ci][0] = fmaf(m.w, w3r.x, acc[ci][0]);
                acc[ci][1] = fmaf(m.w, w3r.y, acc[ci][1]);
                acc[ci][2] = fmaf(m.w, w3r.z, acc[ci][2]);
                acc[ci][3] = fmaf(m.w, w3r.w, acc[ci][3]);
            }
        }
        __syncthreads();   // all s_mc reads done; now overlay with m_part^T
        #pragma unroll
        for (int jj = 0; jj < 4; ++jj)
            #pragma unroll
            for (int ci = 0; ci < 4; ++ci)
                s_mc[(j0 + jj) * PITCH + c_lo + 16 * ci] = acc[ci][jj];  // 2-way, free
    }
    __syncthreads();

    // ---- phase B: 2b x 4c per thread; a1 c-vectorized via m_part^T float4 ----
    const int bq = (tid & 15) << 1;
    const int cq = (tid >> 4) << 2;
    float4 a1v[2];
    a1v[0] = make_float4(0.f, 0.f, 0.f, 0.f);
    a1v[1] = make_float4(0.f, 0.f, 0.f, 0.f);
    float a2[2][4] = {{0.f}};
    const float* mxb = mctx + (size_t)C0 * 64;

    #pragma unroll 4
    for (int j4 = 0; j4 < 16; ++j4) {
        const int jo = j4 * 4;
        float4 w2v = *(const float4*)(W2 + jo);                       // uniform -> s_load
        float4 qp0 = *(const float4*)&s_qp[ bq      * PITCH + jo];
        float4 qp1 = *(const float4*)&s_qp[(bq + 1) * PITCH + jo];
        float4 qn0 = *(const float4*)&s_qn[ bq      * PITCH + jo];
        float4 qn1 = *(const float4*)&s_qn[(bq + 1) * PITCH + jo];
        float4 m0 = *(const float4*)&s_mc[(jo + 0) * PITCH + cq];     // float4 over c
        float4 m1 = *(const float4*)&s_mc[(jo + 1) * PITCH + cq];
        float4 m2 = *(const float4*)&s_mc[(jo + 2) * PITCH + cq];
        float4 m3 = *(const float4*)&s_mc[(jo + 3) * PITCH + cq];

        #pragma unroll
        for (int bi = 0; bi < 2; ++bi) {
            float4 qp = bi ? qp1 : qp0;
            float4& av = a1v[bi];
            av.x = fmaf(fmaxf(qp.x + m0.x, 0.f), w2v.x, av.x);
            av.y = fmaf(fmaxf(qp.x + m0.y, 0.f), w2v.x, av.y);
            av.z = fmaf(fmaxf(qp.x + m0.z, 0.f), w2v.x, av.z);
            av.w = fmaf(fmaxf(qp.x + m0.w, 0.f), w2v.x, av.w);
            av.x = fmaf(fmaxf(qp.y + m1.x, 0.f), w2v.y, av.x);
            av.y = fmaf(fmaxf(qp.y + m1.y, 0.f), w2v.y, av.y);
            av.z = fmaf(fmaxf(qp.y + m1.z, 0.f), w2v.y, av.z);
            av.w = fmaf(fmaxf(qp.y + m1.w, 0.f), w2v.y, av.w);
            av.x = fmaf(fmaxf(qp.z + m2.x, 0.f), w2v.z, av.x);
            av.y = fmaf(fmaxf(qp.z + m2.y, 0.f), w2v.z, av.y);
            av.z = fmaf(fmaxf(qp.z + m2.z, 0.f), w2v.z, av.z);
            av.w = fmaf(fmaxf(qp.z + m2.w, 0.f), w2v.z, av.w);
            av.x = fmaf(fmaxf(qp.w + m3.x, 0.f), w2v.w, av.x);
            av.y = fmaf(fmaxf(qp.w + m3.y, 0.f), w2v.w, av.y);
            av.z = fmaf(fmaxf(qp.w + m3.z, 0.f), w2v.w, av.z);
            av.w = fmaf(fmaxf(qp.w + m3.w, 0.f), w2v.w, av.w);
        }
        #pragma unroll
        for (int ci = 0; ci < 4; ++ci) {
            float4 xv = *(const float4*)&mxb[(cq + ci) * 64 + jo];    // L1-hot
            a2[0][ci] = fmaf(qn0.x, xv.x, a2[0][ci]);
            a2[0][ci] = fmaf(qn0.y, xv.y, a2[0][ci]);
            a2[0][ci] = fmaf(qn0.z, xv.z, a2[0][ci]);
            a2[0][ci] = fmaf(qn0.w, xv.w, a2[0][ci]);
            a2[1][ci] = fmaf(qn1.x, xv.x, a2[1][ci]);
            a2[1][ci] = fmaf(qn1.y, xv.y, a2[1][ci]);
            a2[1][ci] = fmaf(qn1.z, xv.z, a2[1][ci]);
            a2[1][ci] = fmaf(qn1.w, xv.w, a2[1][ci]);
        }
    }

    // ---- epilogue: dense float4 stores, 2 per thread ----
    const float b2v = b2[0];
    float4 inv4  = *(const float4*)&s_inv[cq];
    float4 base4 = *(const float4*)&s_base[cq];
    #pragma unroll
    for (int bi = 0; bi < 2; ++bi) {
        float4 r;
        r.x = 0.5f / (1.f + expf(-(a1v[bi].x + b2v))) + a2[bi][0] * inv4.x + base4.x;
        r.y = 0.5f / (1.f + expf(-(a1v[bi].y + b2v))) + a2[bi][1] * inv4.y + base4.y;
        r.z = 0.5f / (1.f + expf(-(a1v[bi].z + b2v))) + a2[bi][2] * inv4.z + base4.z;
        r.w = 0.5f / (1.f + expf(-(a1v[bi].w + b2v))) + a2[bi][3] * inv4.w + base4.w;
        *(float4*)&ws[WS_FINAL + (size_t)(bq + bi) * CAP + C0 + cq] = r;
    }
}

// ---- top-k phase 1: one wave per (row, 1024-chunk), register-resident ----
__global__ __launch_bounds__(64) void topk_part1(float* __restrict__ ws)
{
    const int lane = threadIdx.x;
    const int b = blockIdx.y;
    float* row = ws + WS_FINAL + (size_t)b * CAP;
    const int cbase = blockIdx.x * CHUNK;

    float v[16];
    #pragma unroll
    for (int g = 0; g < 4; ++g) {
        float4 t = *(const float4*)&row[cbase + g * 256 + lane * 4];
        v[4 * g + 0] = t.x; v[4 * g + 1] = t.y;
        v[4 * g + 2] = t.z; v[4 * g + 3] = t.w;
    }

    float outv = 0.f;
    int   outi = 0;

    for (int k = 0; k < TOPK; ++k) {
        float bv = v[0]; int bj = 0;
        #pragma unroll
        for (int j = 1; j < 16; ++j)
            if (v[j] > bv) { bv = v[j]; bj = j; }
        int bi = cbase + (bj >> 2) * 256 + lane * 4 + (bj & 3);

        #pragma unroll
        for (int off = 1; off < 64; off <<= 1) {
            float ov = __shfl_xor(bv, off, 64);
            int   oi = __shfl_xor(bi, off, 64);
            if (ov > bv || (ov == bv && oi < bi)) { bv = ov; bi = oi; }
        }
        if (lane == k) { outv = bv; outi = bi; }

        int rel = bi - cbase;
        bool mine = (((rel >> 2) & 63) == lane);
        int wj = ((rel >> 8) << 2) | (rel & 3);
        #pragma unroll
        for (int j = 0; j < 16; ++j)
            if (mine && wj == j) v[j] = -INFINITY;
    }

    if (lane < TOPK) {
        row[cbase + lane]        = outv;
        row[cbase + TOPK + lane] = __int_as_float(outi);
    }
}

// ---- top-k phase 2: one wave per row, merge 32x16 candidates + fused gather ----
__global__ __launch_bounds__(64) void topk_part2(
    const float* __restrict__ mcont,
    const float* __restrict__ fresh,
    const float* __restrict__ ws,
    float* __restrict__ out)
{
    const int lane = threadIdx.x;
    const int b = blockIdx.x;
    const float* row = ws + WS_FINAL + (size_t)b * CAP;

    float* out_content = out;                       // [32][16][64]
    float* out_sim     = out + NB * TOPK * 64;      // [32][16]
    float* out_tw      = out + NB * TOPK * 64 + NB * TOPK;

    // 512 candidates (32 chunks x 16), 8 per lane; cand = s*64 + lane -> coalesced
    float v[8]; int iv[8];
    #pragma unroll
    for (int s = 0; s < 8; ++s) {
        int cand = s * 64 + lane;
        int ch = cand >> 4, pos = cand & 15;
        v[s]  = row[ch * CHUNK + pos];
        iv[s] = __float_as_int(row[ch * CHUNK + TOPK + pos]);
    }

    float wval = 0.f; int widx = 0;
    for (int k = 0; k < TOPK; ++k) {
        float bv = v[0]; int bi = iv[0];
        #pragma unroll
        for (int s = 1; s < 8; ++s)
            if (v[s] > bv || (v[s] == bv && iv[s] < bi)) { bv = v[s]; bi = iv[s]; }
        #pragma unroll
        for (int off = 1; off < 64; off <<= 1) {
            float ov = __shfl_xor(bv, off, 64);
            int   oi = __shfl_xor(bi, off, 64);
            if (ov > bv || (ov == bv && oi < bi)) { bv = ov; bi = oi; }
        }
        if (lane == k) { wval = bv; widx = bi; }
        #pragma unroll
        for (int s = 0; s < 8; ++s)
            if (iv[s] == bi) v[s] = -INFINITY;
    }

    if (lane < TOPK) {
        out_sim[b * TOPK + lane] = wval;
        out_tw [b * TOPK + lane] = fresh[widx];
    }

    #pragma unroll
    for (int r = 0; r < TOPK; ++r) {
        int wi = __shfl(widx, r, 64);
        out_content[(size_t)b * TOPK * 64 + r * 64 + lane] =
            mcont[(size_t)wi * 64 + lane];
    }
}

extern "C" void kernel_launch(void* const* d_in, const int* in_sizes, int n_in,
                              void* d_out, int out_size, void* d_ws, size_t ws_size,
                              hipStream_t stream) {
    const float* qc    = (const float*)d_in[0];
    const float* qctx  = (const float*)d_in[1];
    const float* mcont = (const float*)d_in[2];
    const float* mctx  = (const float*)d_in[3];
    const float* fresh = (const float*)d_in[4];
    const float* W1    = (const float*)d_in[5];
    const float* b1    = (const float*)d_in[6];
    const float* W2    = (const float*)d_in[7];
    const float* b2    = (const float*)d_in[8];
    float* out = (float*)d_out;
    float* ws  = (float*)d_ws;

    score_kernel<<<NBLK, 256, 0, stream>>>(qc, qctx, mcont, mctx, fresh,
                                           W1, b1, W2, b2, ws);
    topk_part1<<<dim3(NCHUNK, NB), 64, 0, stream>>>(ws);
    topk_part2<<<NB, 64, 0, stream>>>(mcont, fresh, ws, out);
}

// Round 2
// 141.268 us; speedup vs baseline: 1.0124x; 1.0124x over previous
//
#include <hip/hip_runtime.h>
#include <math.h>

#define CAP   32768
#define NB    32
#define ROWS  64
#define NBLK  (CAP / ROWS)   // 512
#define TOPK  16
#define CEPS  1e-8f

#define PITCH 68              // LDS row pitch (floats); 16B-aligned rows
#define CHUNK 2048
#define NCHUNK (CAP / CHUNK)  // 16

// ws layout (floats)
#define WS_QP    0            // [32][64] q_part + b1
#define WS_QN    2048         // [32][64] normalized query context
#define WS_FINAL 4096         // [32][32768] final scores

__global__ __launch_bounds__(64) void prep_kernel(
    const float* __restrict__ qc,    // [32][64]
    const float* __restrict__ qctx,  // [32][64]
    const float* __restrict__ W1,    // [128][64]
    const float* __restrict__ b1,    // [64]
    float* __restrict__ ws)
{
    const int b = blockIdx.x;
    const int j = threadIdx.x;

    float a0 = b1[j], a1 = 0.f, a2 = 0.f, a3 = 0.f;
    #pragma unroll
    for (int i = 0; i < 64; i += 4) {
        a0 = fmaf(qc[b * 64 + i + 0], W1[(i + 0) * 64 + j], a0);
        a1 = fmaf(qc[b * 64 + i + 1], W1[(i + 1) * 64 + j], a1);
        a2 = fmaf(qc[b * 64 + i + 2], W1[(i + 2) * 64 + j], a2);
        a3 = fmaf(qc[b * 64 + i + 3], W1[(i + 3) * 64 + j], a3);
    }
    ws[WS_QP + b * 64 + j] = (a0 + a1) + (a2 + a3);

    float x = qctx[b * 64 + j];
    float ss = x * x;
    ss += __shfl_xor(ss, 1,  64);
    ss += __shfl_xor(ss, 2,  64);
    ss += __shfl_xor(ss, 4,  64);
    ss += __shfl_xor(ss, 8,  64);
    ss += __shfl_xor(ss, 16, 64);
    ss += __shfl_xor(ss, 32, 64);
    ws[WS_QN + b * 64 + j] = x / fmaxf(sqrtf(ss), CEPS);
}

__global__ __launch_bounds__(256) void score_kernel(
    const float* __restrict__ mcont,  // [CAP][64]
    const float* __restrict__ mctx,   // [CAP][64]
    const float* __restrict__ fresh,  // [CAP]
    const float* __restrict__ W1,     // [128][64]
    const float* __restrict__ W2,     // [64]
    const float* __restrict__ b2,     // [1]
    float* __restrict__ ws)
{
    __shared__ float s_mc[ROWS * PITCH];   // mc tile; after phase A: m_part^T [j][c]
    __shared__ float s_qp[NB * PITCH];
    __shared__ float s_qn[NB * PITCH];
    __shared__ float s_base[ROWS];         // 0.2 * freshness
    __shared__ float s_inv[ROWS];          // 0.3 / max(||mctx||, eps)

    const int tid = threadIdx.x;
    const int C0 = blockIdx.x * ROWS;

    // ---- staging: mc tile (coalesced), qp/qn, mctx norms ----
    const float4* g_mc = (const float4*)(mcont + (size_t)C0 * 64);
    #pragma unroll
    for (int t = tid; t < ROWS * 16; t += 256) {
        int r = t >> 4, c4 = t & 15;
        *(float4*)&s_mc[r * PITCH + c4 * 4] = g_mc[t];
    }
    const float4* g_qp = (const float4*)(ws + WS_QP);
    const float4* g_qn = (const float4*)(ws + WS_QN);
    #pragma unroll
    for (int t = tid; t < NB * 16; t += 256) {
        int r = t >> 4, c4 = t & 15;
        *(float4*)&s_qp[r * PITCH + c4 * 4] = g_qp[t];
        *(float4*)&s_qn[r * PITCH + c4 * 4] = g_qn[t];
    }
    {   // mctx norms: thread t -> row r=t>>2, quarter q=t&3 (coalesced b128 loads)
        const int r = tid >> 2, q = tid & 3;
        const float* xr = mctx + (size_t)(C0 + r) * 64 + q * 16;
        float ss = 0.f;
        #pragma unroll
        for (int i = 0; i < 4; ++i) {
            float4 x = *(const float4*)&xr[i * 4];
            ss = fmaf(x.x, x.x, ss); ss = fmaf(x.y, x.y, ss);
            ss = fmaf(x.z, x.z, ss); ss = fmaf(x.w, x.w, ss);
        }
        ss += __shfl_xor(ss, 1, 64);
        ss += __shfl_xor(ss, 2, 64);
        if (q == 0) {
            s_inv[r]  = 0.3f / fmaxf(sqrtf(ss), CEPS);
            s_base[r] = 0.2f * fresh[C0 + r];
        }
    }
    __syncthreads();

    // ---- phase A: m_part = MC @ W1lo, 4c x 4j register tile.
    //      mc rows from LDS (stride 68 -> 2-way, free); W1 from global (broadcast, L1-hot)
    const int c_lo = tid & 15;
    const int j0 = (tid >> 4) * 4;
    {
        float acc[4][4] = {{0.f}};
        #pragma unroll 4
        for (int i4 = 0; i4 < 16; ++i4) {
            float4 w0 = *(const float4*)&W1[(64 + i4 * 4 + 0) * 64 + j0];
            float4 w1r = *(const float4*)&W1[(64 + i4 * 4 + 1) * 64 + j0];
            float4 w2r = *(const float4*)&W1[(64 + i4 * 4 + 2) * 64 + j0];
            float4 w3r = *(const float4*)&W1[(64 + i4 * 4 + 3) * 64 + j0];
            #pragma unroll
            for (int ci = 0; ci < 4; ++ci) {
                float4 m = *(const float4*)&s_mc[(c_lo + 16 * ci) * PITCH + i4 * 4];
                acc[ci][0] = fmaf(m.x, w0.x, acc[ci][0]);
                acc[ci][1] = fmaf(m.x, w0.y, acc[ci][1]);
                acc[ci][2] = fmaf(m.x, w0.z, acc[ci][2]);
                acc[ci][3] = fmaf(m.x, w0.w, acc[ci][3]);
                acc[ci][0] = fmaf(m.y, w1r.x, acc[ci][0]);
                acc[ci][1] = fmaf(m.y, w1r.y, acc[ci][1]);
                acc[ci][2] = fmaf(m.y, w1r.z, acc[ci][2]);
                acc[ci][3] = fmaf(m.y, w1r.w, acc[ci][3]);
                acc[ci][0] = fmaf(m.z, w2r.x, acc[ci][0]);
                acc[ci][1] = fmaf(m.z, w2r.y, acc[ci][1]);
                acc[ci][2] = fmaf(m.z, w2r.z, acc[ci][2]);
                acc[ci][3] = fmaf(m.z, w2r.w, acc[ci][3]);
                acc[ci][0] = fmaf(m.w, w3r.x, acc[ci][0]);
                acc[ci][1] = fmaf(m.w, w3r.y, acc[ci][1]);
                acc[ci][2] = fmaf(m.w, w3r.z, acc[ci][2]);
                acc[ci][3] = fmaf(m.w, w3r.w, acc[ci][3]);
            }
        }
        __syncthreads();   // all s_mc reads done; now overlay with m_part^T
        #pragma unroll
        for (int jj = 0; jj < 4; ++jj)
            #pragma unroll
            for (int ci = 0; ci < 4; ++ci)
                s_mc[(j0 + jj) * PITCH + c_lo + 16 * ci] = acc[ci][jj];  // 2-way, free
    }
    __syncthreads();

    // ---- phase B: 2b x 4c per thread; a1 c-vectorized via m_part^T float4 ----
    const int bq = (tid & 15) << 1;
    const int cq = (tid >> 4) << 2;
    float4 a1v[2];
    a1v[0] = make_float4(0.f, 0.f, 0.f, 0.f);
    a1v[1] = make_float4(0.f, 0.f, 0.f, 0.f);
    float a2[2][4] = {{0.f}};
    const float* mxb = mctx + (size_t)C0 * 64;

    #pragma unroll 4
    for (int j4 = 0; j4 < 16; ++j4) {
        const int jo = j4 * 4;
        float4 w2v = *(const float4*)(W2 + jo);                       // uniform -> s_load
        float4 qp0 = *(const float4*)&s_qp[ bq      * PITCH + jo];
        float4 qp1 = *(const float4*)&s_qp[(bq + 1) * PITCH + jo];
        float4 qn0 = *(const float4*)&s_qn[ bq      * PITCH + jo];
        float4 qn1 = *(const float4*)&s_qn[(bq + 1) * PITCH + jo];
        float4 m0 = *(const float4*)&s_mc[(jo + 0) * PITCH + cq];     // float4 over c
        float4 m1 = *(const float4*)&s_mc[(jo + 1) * PITCH + cq];
        float4 m2 = *(const float4*)&s_mc[(jo + 2) * PITCH + cq];
        float4 m3 = *(const float4*)&s_mc[(jo + 3) * PITCH + cq];

        #pragma unroll
        for (int bi = 0; bi < 2; ++bi) {
            float4 qp = bi ? qp1 : qp0;
            float4& av = a1v[bi];
            av.x = fmaf(fmaxf(qp.x + m0.x, 0.f), w2v.x, av.x);
            av.y = fmaf(fmaxf(qp.x + m0.y, 0.f), w2v.x, av.y);
            av.z = fmaf(fmaxf(qp.x + m0.z, 0.f), w2v.x, av.z);
            av.w = fmaf(fmaxf(qp.x + m0.w, 0.f), w2v.x, av.w);
            av.x = fmaf(fmaxf(qp.y + m1.x, 0.f), w2v.y, av.x);
            av.y = fmaf(fmaxf(qp.y + m1.y, 0.f), w2v.y, av.y);
            av.z = fmaf(fmaxf(qp.y + m1.z, 0.f), w2v.y, av.z);
            av.w = fmaf(fmaxf(qp.y + m1.w, 0.f), w2v.y, av.w);
            av.x = fmaf(fmaxf(qp.z + m2.x, 0.f), w2v.z, av.x);
            av.y = fmaf(fmaxf(qp.z + m2.y, 0.f), w2v.z, av.y);
            av.z = fmaf(fmaxf(qp.z + m2.z, 0.f), w2v.z, av.z);
            av.w = fmaf(fmaxf(qp.z + m2.w, 0.f), w2v.z, av.w);
            av.x = fmaf(fmaxf(qp.w + m3.x, 0.f), w2v.w, av.x);
            av.y = fmaf(fmaxf(qp.w + m3.y, 0.f), w2v.w, av.y);
            av.z = fmaf(fmaxf(qp.w + m3.z, 0.f), w2v.w, av.z);
            av.w = fmaf(fmaxf(qp.w + m3.w, 0.f), w2v.w, av.w);
        }
        #pragma unroll
        for (int ci = 0; ci < 4; ++ci) {
            float4 xv = *(const float4*)&mxb[(cq + ci) * 64 + jo];    // L1-hot
            a2[0][ci] = fmaf(qn0.x, xv.x, a2[0][ci]);
            a2[0][ci] = fmaf(qn0.y, xv.y, a2[0][ci]);
            a2[0][ci] = fmaf(qn0.z, xv.z, a2[0][ci]);
            a2[0][ci] = fmaf(qn0.w, xv.w, a2[0][ci]);
            a2[1][ci] = fmaf(qn1.x, xv.x, a2[1][ci]);
            a2[1][ci] = fmaf(qn1.y, xv.y, a2[1][ci]);
            a2[1][ci] = fmaf(qn1.z, xv.z, a2[1][ci]);
            a2[1][ci] = fmaf(qn1.w, xv.w, a2[1][ci]);
        }
    }

    // ---- epilogue: dense float4 stores, 2 per thread ----
    const float b2v = b2[0];
    float4 inv4  = *(const float4*)&s_inv[cq];
    float4 base4 = *(const float4*)&s_base[cq];
    #pragma unroll
    for (int bi = 0; bi < 2; ++bi) {
        float4 r;
        r.x = 0.5f / (1.f + expf(-(a1v[bi].x + b2v))) + a2[bi][0] * inv4.x + base4.x;
        r.y = 0.5f / (1.f + expf(-(a1v[bi].y + b2v))) + a2[bi][1] * inv4.y + base4.y;
        r.z = 0.5f / (1.f + expf(-(a1v[bi].z + b2v))) + a2[bi][2] * inv4.z + base4.z;
        r.w = 0.5f / (1.f + expf(-(a1v[bi].w + b2v))) + a2[bi][3] * inv4.w + base4.w;
        *(float4*)&ws[WS_FINAL + (size_t)(bq + bi) * CAP + C0 + cq] = r;
    }
}

// ---- fused top-k: one block (16 waves) per row.
//      Stage 1: wave w extracts top-16 of chunk w (2048 scores, register-resident)
//               -- identical comparison/ordering semantics to the old topk_part1.
//      Stage 2: wave 0 merges 16x16=256 candidates from LDS + fused gather
//               -- identical comparison semantics to the old topk_part2.
__global__ __launch_bounds__(1024) void topk_fused(
    const float* __restrict__ mcont,
    const float* __restrict__ fresh,
    const float* __restrict__ ws,
    float* __restrict__ out)
{
    __shared__ float s_val[NCHUNK * TOPK];   // 256 candidates
    __shared__ int   s_idx[NCHUNK * TOPK];

    const int lane = threadIdx.x & 63;
    const int w    = threadIdx.x >> 6;       // wave id = chunk id, 0..15
    const int b    = blockIdx.x;
    const float* row = ws + WS_FINAL + (size_t)b * CAP;
    const int cbase = w * CHUNK;

    // ---- stage 1: per-wave top-16 of 2048 ----
    float v[32];
    #pragma unroll
    for (int g = 0; g < 8; ++g) {
        float4 t = *(const float4*)&row[cbase + g * 256 + lane * 4];
        v[4 * g + 0] = t.x; v[4 * g + 1] = t.y;
        v[4 * g + 2] = t.z; v[4 * g + 3] = t.w;
    }

    float outv = 0.f;
    int   outi = 0;

    for (int k = 0; k < TOPK; ++k) {
        float bv = v[0]; int bj = 0;
        #pragma unroll
        for (int j = 1; j < 32; ++j)
            if (v[j] > bv) { bv = v[j]; bj = j; }
        int bi = cbase + (bj >> 2) * 256 + lane * 4 + (bj & 3);

        #pragma unroll
        for (int off = 1; off < 64; off <<= 1) {
            float ov = __shfl_xor(bv, off, 64);
            int   oi = __shfl_xor(bi, off, 64);
            if (ov > bv || (ov == bv && oi < bi)) { bv = ov; bi = oi; }
        }
        if (lane == k) { outv = bv; outi = bi; }

        int rel = bi - cbase;
        bool mine = (((rel >> 2) & 63) == lane);
        int wj = ((rel >> 8) << 2) | (rel & 3);
        #pragma unroll
        for (int j = 0; j < 32; ++j)
            if (mine && wj == j) v[j] = -INFINITY;
    }

    if (lane < TOPK) {
        s_val[w * TOPK + lane] = outv;
        s_idx[w * TOPK + lane] = outi;
    }
    __syncthreads();

    // ---- stage 2: wave 0 merges 256 candidates + gather ----
    if (w != 0) return;

    float* out_content = out;                       // [32][16][64]
    float* out_sim     = out + NB * TOPK * 64;      // [32][16]
    float* out_tw      = out + NB * TOPK * 64 + NB * TOPK;

    float mv[4]; int mi[4];
    #pragma unroll
    for (int s = 0; s < 4; ++s) {
        int cand = s * 64 + lane;                   // = ch*16 + pos, linear
        mv[s] = s_val[cand];
        mi[s] = s_idx[cand];
    }

    float wval = 0.f; int widx = 0;
    for (int k = 0; k < TOPK; ++k) {
        float bv = mv[0]; int bi = mi[0];
        #pragma unroll
        for (int s = 1; s < 4; ++s)
            if (mv[s] > bv || (mv[s] == bv && mi[s] < bi)) { bv = mv[s]; bi = mi[s]; }
        #pragma unroll
        for (int off = 1; off < 64; off <<= 1) {
            float ov = __shfl_xor(bv, off, 64);
            int   oi = __shfl_xor(bi, off, 64);
            if (ov > bv || (ov == bv && oi < bi)) { bv = ov; bi = oi; }
        }
        if (lane == k) { wval = bv; widx = bi; }
        #pragma unroll
        for (int s = 0; s < 4; ++s)
            if (mi[s] == bi) mv[s] = -INFINITY;
    }

    if (lane < TOPK) {
        out_sim[b * TOPK + lane] = wval;
        out_tw [b * TOPK + lane] = fresh[widx];
    }

    #pragma unroll
    for (int r = 0; r < TOPK; ++r) {
        int wi = __shfl(widx, r, 64);
        out_content[(size_t)b * TOPK * 64 + r * 64 + lane] =
            mcont[(size_t)wi * 64 + lane];
    }
}

extern "C" void kernel_launch(void* const* d_in, const int* in_sizes, int n_in,
                              void* d_out, int out_size, void* d_ws, size_t ws_size,
                              hipStream_t stream) {
    const float* qc    = (const float*)d_in[0];
    const float* qctx  = (const float*)d_in[1];
    const float* mcont = (const float*)d_in[2];
    const float* mctx  = (const float*)d_in[3];
    const float* fresh = (const float*)d_in[4];
    const float* W1    = (const float*)d_in[5];
    const float* b1    = (const float*)d_in[6];
    const float* W2    = (const float*)d_in[7];
    const float* b2    = (const float*)d_in[8];
    float* out = (float*)d_out;
    float* ws  = (float*)d_ws;

    prep_kernel<<<NB, 64, 0, stream>>>(qc, qctx, W1, b1, ws);
    score_kernel<<<NBLK, 256, 0, stream>>>(mcont, mctx, fresh, W1, W2, b2, ws);
    topk_fused<<<NB, 1024, 0, stream>>>(mcont, fresh, ws, out);
}

// Round 3
// 125.880 us; speedup vs baseline: 1.1361x; 1.1222x over previous
//
#include <hip/hip_runtime.h>
#include <math.h>

#define CAP   32768
#define NB    32
#define ROWS  64
#define NBLK  (CAP / ROWS)   // 512
#define TOPK  16
#define CEPS  1e-8f

#define PITCH 68              // LDS row pitch (floats); 16B-aligned rows
#define CHUNK 2048
#define NCHUNK (CAP / CHUNK)  // 16

// ws layout (floats)
#define WS_QP    0            // [32][64] q_part + b1
#define WS_QN    2048         // [32][64] normalized query context
#define WS_FINAL 4096         // [32][32768] final scores

__global__ __launch_bounds__(64) void prep_kernel(
    const float* __restrict__ qc,    // [32][64]
    const float* __restrict__ qctx,  // [32][64]
    const float* __restrict__ W1,    // [128][64]
    const float* __restrict__ b1,    // [64]
    float* __restrict__ ws)
{
    const int b = blockIdx.x;
    const int j = threadIdx.x;

    float a0 = b1[j], a1 = 0.f, a2 = 0.f, a3 = 0.f;
    #pragma unroll
    for (int i = 0; i < 64; i += 4) {
        a0 = fmaf(qc[b * 64 + i + 0], W1[(i + 0) * 64 + j], a0);
        a1 = fmaf(qc[b * 64 + i + 1], W1[(i + 1) * 64 + j], a1);
        a2 = fmaf(qc[b * 64 + i + 2], W1[(i + 2) * 64 + j], a2);
        a3 = fmaf(qc[b * 64 + i + 3], W1[(i + 3) * 64 + j], a3);
    }
    ws[WS_QP + b * 64 + j] = (a0 + a1) + (a2 + a3);

    float x = qctx[b * 64 + j];
    float ss = x * x;
    ss += __shfl_xor(ss, 1,  64);
    ss += __shfl_xor(ss, 2,  64);
    ss += __shfl_xor(ss, 4,  64);
    ss += __shfl_xor(ss, 8,  64);
    ss += __shfl_xor(ss, 16, 64);
    ss += __shfl_xor(ss, 32, 64);
    ws[WS_QN + b * 64 + j] = x / fmaxf(sqrtf(ss), CEPS);
}

__global__ __launch_bounds__(256) void score_kernel(
    const float* __restrict__ mcont,  // [CAP][64]
    const float* __restrict__ mctx,   // [CAP][64]
    const float* __restrict__ fresh,  // [CAP]
    const float* __restrict__ W1,     // [128][64]
    const float* __restrict__ W2,     // [64]
    const float* __restrict__ b2,     // [1]
    float* __restrict__ ws)
{
    __shared__ float s_mc[ROWS * PITCH];   // mc tile; after phase A: m_part^T [j][c]
    __shared__ float s_qp[NB * PITCH];
    __shared__ float s_qn[NB * PITCH];
    __shared__ float s_base[ROWS];         // 0.2 * freshness
    __shared__ float s_inv[ROWS];          // 0.3 / max(||mctx||, eps)

    const int tid = threadIdx.x;
    const int C0 = blockIdx.x * ROWS;

    // ---- staging: mc tile (coalesced), qp/qn, mctx norms ----
    const float4* g_mc = (const float4*)(mcont + (size_t)C0 * 64);
    #pragma unroll
    for (int t = tid; t < ROWS * 16; t += 256) {
        int r = t >> 4, c4 = t & 15;
        *(float4*)&s_mc[r * PITCH + c4 * 4] = g_mc[t];
    }
    const float4* g_qp = (const float4*)(ws + WS_QP);
    const float4* g_qn = (const float4*)(ws + WS_QN);
    #pragma unroll
    for (int t = tid; t < NB * 16; t += 256) {
        int r = t >> 4, c4 = t & 15;
        *(float4*)&s_qp[r * PITCH + c4 * 4] = g_qp[t];
        *(float4*)&s_qn[r * PITCH + c4 * 4] = g_qn[t];
    }
    {   // mctx norms: thread t -> row r=t>>2, quarter q=t&3 (coalesced b128 loads)
        const int r = tid >> 2, q = tid & 3;
        const float* xr = mctx + (size_t)(C0 + r) * 64 + q * 16;
        float ss = 0.f;
        #pragma unroll
        for (int i = 0; i < 4; ++i) {
            float4 x = *(const float4*)&xr[i * 4];
            ss = fmaf(x.x, x.x, ss); ss = fmaf(x.y, x.y, ss);
            ss = fmaf(x.z, x.z, ss); ss = fmaf(x.w, x.w, ss);
        }
        ss += __shfl_xor(ss, 1, 64);
        ss += __shfl_xor(ss, 2, 64);
        if (q == 0) {
            s_inv[r]  = 0.3f / fmaxf(sqrtf(ss), CEPS);
            s_base[r] = 0.2f * fresh[C0 + r];
        }
    }
    __syncthreads();

    // ---- phase A: m_part = MC @ W1lo, 4c x 4j register tile.
    //      mc rows from LDS (stride 68 -> 2-way, free); W1 from global (broadcast, L1-hot)
    const int c_lo = tid & 15;
    const int j0 = (tid >> 4) * 4;
    {
        float acc[4][4] = {{0.f}};
        #pragma unroll 4
        for (int i4 = 0; i4 < 16; ++i4) {
            float4 w0 = *(const float4*)&W1[(64 + i4 * 4 + 0) * 64 + j0];
            float4 w1r = *(const float4*)&W1[(64 + i4 * 4 + 1) * 64 + j0];
            float4 w2r = *(const float4*)&W1[(64 + i4 * 4 + 2) * 64 + j0];
            float4 w3r = *(const float4*)&W1[(64 + i4 * 4 + 3) * 64 + j0];
            #pragma unroll
            for (int ci = 0; ci < 4; ++ci) {
                float4 m = *(const float4*)&s_mc[(c_lo + 16 * ci) * PITCH + i4 * 4];
                acc[ci][0] = fmaf(m.x, w0.x, acc[ci][0]);
                acc[ci][1] = fmaf(m.x, w0.y, acc[ci][1]);
                acc[ci][2] = fmaf(m.x, w0.z, acc[ci][2]);
                acc[ci][3] = fmaf(m.x, w0.w, acc[ci][3]);
                acc[ci][0] = fmaf(m.y, w1r.x, acc[ci][0]);
                acc[ci][1] = fmaf(m.y, w1r.y, acc[ci][1]);
                acc[ci][2] = fmaf(m.y, w1r.z, acc[ci][2]);
                acc[ci][3] = fmaf(m.y, w1r.w, acc[ci][3]);
                acc[ci][0] = fmaf(m.z, w2r.x, acc[ci][0]);
                acc[ci][1] = fmaf(m.z, w2r.y, acc[ci][1]);
                acc[ci][2] = fmaf(m.z, w2r.z, acc[ci][2]);
                acc[ci][3] = fmaf(m.z, w2r.w, acc[ci][3]);
                acc[ci][0] = fmaf(m.w, w3r.x, acc[ci][0]);
                acc[ci][1] = fmaf(m.w, w3r.y, acc[ci][1]);
                acc[ci][2] = fmaf(m.w, w3r.z, acc[ci][2]);
                acc[ci][3] = fmaf(m.w, w3r.w, acc[ci][3]);
            }
        }
        __syncthreads();   // all s_mc reads done; now overlay with m_part^T
        #pragma unroll
        for (int jj = 0; jj < 4; ++jj)
            #pragma unroll
            for (int ci = 0; ci < 4; ++ci)
                s_mc[(j0 + jj) * PITCH + c_lo + 16 * ci] = acc[ci][jj];  // 2-way, free
    }
    __syncthreads();

    // ---- phase B: 2b x 4c per thread; a1 c-vectorized via m_part^T float4 ----
    const int bq = (tid & 15) << 1;
    const int cq = (tid >> 4) << 2;
    float4 a1v[2];
    a1v[0] = make_float4(0.f, 0.f, 0.f, 0.f);
    a1v[1] = make_float4(0.f, 0.f, 0.f, 0.f);
    float a2[2][4] = {{0.f}};
    const float* mxb = mctx + (size_t)C0 * 64;

    #pragma unroll 4
    for (int j4 = 0; j4 < 16; ++j4) {
        const int jo = j4 * 4;
        float4 w2v = *(const float4*)(W2 + jo);                       // uniform -> s_load
        float4 qp0 = *(const float4*)&s_qp[ bq      * PITCH + jo];
        float4 qp1 = *(const float4*)&s_qp[(bq + 1) * PITCH + jo];
        float4 qn0 = *(const float4*)&s_qn[ bq      * PITCH + jo];
        float4 qn1 = *(const float4*)&s_qn[(bq + 1) * PITCH + jo];
        float4 m0 = *(const float4*)&s_mc[(jo + 0) * PITCH + cq];     // float4 over c
        float4 m1 = *(const float4*)&s_mc[(jo + 1) * PITCH + cq];
        float4 m2 = *(const float4*)&s_mc[(jo + 2) * PITCH + cq];
        float4 m3 = *(const float4*)&s_mc[(jo + 3) * PITCH + cq];

        #pragma unroll
        for (int bi = 0; bi < 2; ++bi) {
            float4 qp = bi ? qp1 : qp0;
            float4& av = a1v[bi];
            av.x = fmaf(fmaxf(qp.x + m0.x, 0.f), w2v.x, av.x);
            av.y = fmaf(fmaxf(qp.x + m0.y, 0.f), w2v.x, av.y);
            av.z = fmaf(fmaxf(qp.x + m0.z, 0.f), w2v.x, av.z);
            av.w = fmaf(fmaxf(qp.x + m0.w, 0.f), w2v.x, av.w);
            av.x = fmaf(fmaxf(qp.y + m1.x, 0.f), w2v.y, av.x);
            av.y = fmaf(fmaxf(qp.y + m1.y, 0.f), w2v.y, av.y);
            av.z = fmaf(fmaxf(qp.y + m1.z, 0.f), w2v.y, av.z);
            av.w = fmaf(fmaxf(qp.y + m1.w, 0.f), w2v.y, av.w);
            av.x = fmaf(fmaxf(qp.z + m2.x, 0.f), w2v.z, av.x);
            av.y = fmaf(fmaxf(qp.z + m2.y, 0.f), w2v.z, av.y);
            av.z = fmaf(fmaxf(qp.z + m2.z, 0.f), w2v.z, av.z);
            av.w = fmaf(fmaxf(qp.z + m2.w, 0.f), w2v.z, av.w);
            av.x = fmaf(fmaxf(qp.w + m3.x, 0.f), w2v.w, av.x);
            av.y = fmaf(fmaxf(qp.w + m3.y, 0.f), w2v.w, av.y);
            av.z = fmaf(fmaxf(qp.w + m3.z, 0.f), w2v.w, av.z);
            av.w = fmaf(fmaxf(qp.w + m3.w, 0.f), w2v.w, av.w);
        }
        #pragma unroll
        for (int ci = 0; ci < 4; ++ci) {
            float4 xv = *(const float4*)&mxb[(cq + ci) * 64 + jo];    // L1-hot
            a2[0][ci] = fmaf(qn0.x, xv.x, a2[0][ci]);
            a2[0][ci] = fmaf(qn0.y, xv.y, a2[0][ci]);
            a2[0][ci] = fmaf(qn0.z, xv.z, a2[0][ci]);
            a2[0][ci] = fmaf(qn0.w, xv.w, a2[0][ci]);
            a2[1][ci] = fmaf(qn1.x, xv.x, a2[1][ci]);
            a2[1][ci] = fmaf(qn1.y, xv.y, a2[1][ci]);
            a2[1][ci] = fmaf(qn1.z, xv.z, a2[1][ci]);
            a2[1][ci] = fmaf(qn1.w, xv.w, a2[1][ci]);
        }
    }

    // ---- epilogue: dense float4 stores, 2 per thread ----
    const float b2v = b2[0];
    float4 inv4  = *(const float4*)&s_inv[cq];
    float4 base4 = *(const float4*)&s_base[cq];
    #pragma unroll
    for (int bi = 0; bi < 2; ++bi) {
        float4 r;
        r.x = 0.5f / (1.f + expf(-(a1v[bi].x + b2v))) + a2[bi][0] * inv4.x + base4.x;
        r.y = 0.5f / (1.f + expf(-(a1v[bi].y + b2v))) + a2[bi][1] * inv4.y + base4.y;
        r.z = 0.5f / (1.f + expf(-(a1v[bi].z + b2v))) + a2[bi][2] * inv4.z + base4.z;
        r.w = 0.5f / (1.f + expf(-(a1v[bi].w + b2v))) + a2[bi][3] * inv4.w + base4.w;
        *(float4*)&ws[WS_FINAL + (size_t)(bq + bi) * CAP + C0 + cq] = r;
    }
}

// Bitonic sort of 64 (val,idx) pairs across a wave, descending by
// (val >, tie: idx <) -- the exact jax.lax.top_k total order.
// After: lane i holds the i-th best pair.
__device__ __forceinline__ void bitonic64_desc(float& v, int& iv, int lane)
{
    #pragma unroll
    for (int k = 2; k <= 64; k <<= 1) {
        #pragma unroll
        for (int j = k >> 1; j > 0; j >>= 1) {
            float ov = __shfl_xor(v, j, 64);
            int   oi = __shfl_xor(iv, j, 64);
            bool low        = (lane & j) == 0;
            bool dirDesc    = (lane & k) == 0;
            bool takeBetter = (low == dirDesc);
            bool otherBetter = (ov > v) || (ov == v && oi < iv);
            if (otherBetter == takeBetter) { v = ov; iv = oi; }
        }
    }
}

// ---- top-k stage 1: one block (4 waves) per (row, 2048-chunk).
//      Each wave: exact top-16 of its 512 elems (register extraction, 8 regs).
//      Wave 0 then bitonic-sorts the 64 candidates -> chunk top-16 to ws.
__global__ __launch_bounds__(256) void topk_stage1(float* __restrict__ ws)
{
    __shared__ float s_val[64];
    __shared__ int   s_idx[64];

    const int lane = threadIdx.x & 63;
    const int w    = threadIdx.x >> 6;     // 0..3, subchunk id
    const int b    = blockIdx.y;
    float* row = ws + WS_FINAL + (size_t)b * CAP;
    const int cbase = blockIdx.x * CHUNK;
    const int sb = cbase + w * 512;

    float v[8];
    #pragma unroll
    for (int g = 0; g < 2; ++g) {
        float4 t = *(const float4*)&row[sb + g * 256 + lane * 4];
        v[4 * g + 0] = t.x; v[4 * g + 1] = t.y;
        v[4 * g + 2] = t.z; v[4 * g + 3] = t.w;
    }

    float outv = 0.f;
    int   outi = 0;

    for (int k = 0; k < TOPK; ++k) {
        float bv = v[0]; int bj = 0;
        #pragma unroll
        for (int j = 1; j < 8; ++j)
            if (v[j] > bv) { bv = v[j]; bj = j; }
        int bi = sb + (bj >> 2) * 256 + lane * 4 + (bj & 3);

        #pragma unroll
        for (int off = 1; off < 64; off <<= 1) {
            float ov = __shfl_xor(bv, off, 64);
            int   oi = __shfl_xor(bi, off, 64);
            if (ov > bv || (ov == bv && oi < bi)) { bv = ov; bi = oi; }
        }
        if (lane == k) { outv = bv; outi = bi; }

        int rel = bi - sb;
        bool mine = (((rel >> 2) & 63) == lane);
        int wj = ((rel >> 8) << 2) | (rel & 3);
        #pragma unroll
        for (int j = 0; j < 8; ++j)
            if (mine && wj == j) v[j] = -INFINITY;
    }

    if (lane < TOPK) {
        s_val[w * TOPK + lane] = outv;
        s_idx[w * TOPK + lane] = outi;
    }
    __syncthreads();
    if (w != 0) return;

    float mv = s_val[lane];
    int   mi = s_idx[lane];
    bitonic64_desc(mv, mi, lane);
    if (lane < TOPK) {
        row[cbase + lane]        = mv;
        row[cbase + TOPK + lane] = __int_as_float(mi);
    }
}

// ---- top-k stage 2: one block (4 waves) per row. 256 candidates ->
//      per-wave bitonic top-16 -> 64 -> wave-0 bitonic -> final 16 + gather.
__global__ __launch_bounds__(256) void topk_stage2(
    const float* __restrict__ mcont,
    const float* __restrict__ fresh,
    const float* __restrict__ ws,
    float* __restrict__ out)
{
    __shared__ float s_val[64];
    __shared__ int   s_idx[64];

    const int lane = threadIdx.x & 63;
    const int w    = threadIdx.x >> 6;     // 0..3
    const int b    = blockIdx.x;
    const float* row = ws + WS_FINAL + (size_t)b * CAP;

    const int ch  = w * 4 + (lane >> 4);
    const int pos = lane & 15;
    float mv = row[ch * CHUNK + pos];
    int   mi = __float_as_int(row[ch * CHUNK + TOPK + pos]);
    bitonic64_desc(mv, mi, lane);

    if (lane < TOPK) {
        s_val[w * TOPK + lane] = mv;
        s_idx[w * TOPK + lane] = mi;
    }
    __syncthreads();
    if (w != 0) return;

    float fv = s_val[lane];
    int   fi = s_idx[lane];
    bitonic64_desc(fv, fi, lane);

    float* out_content = out;                       // [32][16][64]
    float* out_sim     = out + NB * TOPK * 64;      // [32][16]
    float* out_tw      = out + NB * TOPK * 64 + NB * TOPK;

    if (lane < TOPK) {
        out_sim[b * TOPK + lane] = fv;
        out_tw [b * TOPK + lane] = fresh[fi];
    }

    #pragma unroll
    for (int r = 0; r < TOPK; ++r) {
        int wi = __shfl(fi, r, 64);
        out_content[(size_t)b * TOPK * 64 + r * 64 + lane] =
            mcont[(size_t)wi * 64 + lane];
    }
}

extern "C" void kernel_launch(void* const* d_in, const int* in_sizes, int n_in,
                              void* d_out, int out_size, void* d_ws, size_t ws_size,
                              hipStream_t stream) {
    const float* qc    = (const float*)d_in[0];
    const float* qctx  = (const float*)d_in[1];
    const float* mcont = (const float*)d_in[2];
    const float* mctx  = (const float*)d_in[3];
    const float* fresh = (const float*)d_in[4];
    const float* W1    = (const float*)d_in[5];
    const float* b1    = (const float*)d_in[6];
    const float* W2    = (const float*)d_in[7];
    const float* b2    = (const float*)d_in[8];
    float* out = (float*)d_out;
    float* ws  = (float*)d_ws;

    prep_kernel<<<NB, 64, 0, stream>>>(qc, qctx, W1, b1, ws);
    score_kernel<<<NBLK, 256, 0, stream>>>(mcont, mctx, fresh, W1, W2, b2, ws);
    topk_stage1<<<dim3(NCHUNK, NB), 256, 0, stream>>>(ws);
    topk_stage2<<<NB, 256, 0, stream>>>(mcont, fresh, ws, out);
}

// Round 7
// 125.489 us; speedup vs baseline: 1.1396x; 1.0031x over previous
//
#include <hip/hip_runtime.h>
#include <math.h>

#define CAP   32768
#define NB    32
#define ROWS  64
#define NBLK  (CAP / ROWS)   // 512
#define TOPK  16
#define CEPS  1e-8f

#define PITCH 68              // LDS row pitch (floats); 16B-aligned rows
#define CHUNK 1024
#define NCHUNK (CAP / CHUNK)  // 32

// ws layout (floats)
#define WS_QP    0            // [32][64] q_part + b1
#define WS_QN    2048         // [32][64] normalized query context
#define WS_FINAL 4096         // [32][32768] final scores

__global__ __launch_bounds__(64) void prep_kernel(
    const float* __restrict__ qc,    // [32][64]
    const float* __restrict__ qctx,  // [32][64]
    const float* __restrict__ W1,    // [128][64]
    const float* __restrict__ b1,    // [64]
    float* __restrict__ ws)
{
    const int b = blockIdx.x;
    const int j = threadIdx.x;

    float a0 = b1[j], a1 = 0.f, a2 = 0.f, a3 = 0.f;
    #pragma unroll
    for (int i = 0; i < 64; i += 4) {
        a0 = fmaf(qc[b * 64 + i + 0], W1[(i + 0) * 64 + j], a0);
        a1 = fmaf(qc[b * 64 + i + 1], W1[(i + 1) * 64 + j], a1);
        a2 = fmaf(qc[b * 64 + i + 2], W1[(i + 2) * 64 + j], a2);
        a3 = fmaf(qc[b * 64 + i + 3], W1[(i + 3) * 64 + j], a3);
    }
    ws[WS_QP + b * 64 + j] = (a0 + a1) + (a2 + a3);

    float x = qctx[b * 64 + j];
    float ss = x * x;
    ss += __shfl_xor(ss, 1,  64);
    ss += __shfl_xor(ss, 2,  64);
    ss += __shfl_xor(ss, 4,  64);
    ss += __shfl_xor(ss, 8,  64);
    ss += __shfl_xor(ss, 16, 64);
    ss += __shfl_xor(ss, 32, 64);
    ws[WS_QN + b * 64 + j] = x / fmaxf(sqrtf(ss), CEPS);
}

__global__ __launch_bounds__(256) void score_kernel(
    const float* __restrict__ mcont,  // [CAP][64]
    const float* __restrict__ mctx,   // [CAP][64]
    const float* __restrict__ fresh,  // [CAP]
    const float* __restrict__ W1,     // [128][64]
    const float* __restrict__ W2,     // [64]
    const float* __restrict__ b2,     // [1]
    float* __restrict__ ws)
{
    __shared__ float s_mc[ROWS * PITCH];   // mc tile; after phase A: m_part^T [j][c]
    __shared__ float s_qp[NB * PITCH];
    __shared__ float s_qn[NB * PITCH];
    __shared__ float s_base[ROWS];         // 0.2 * freshness
    __shared__ float s_inv[ROWS];          // 0.3 / max(||mctx||, eps)

    const int tid = threadIdx.x;
    const int C0 = blockIdx.x * ROWS;

    // ---- staging: mc tile (coalesced), qp/qn, mctx norms ----
    const float4* g_mc = (const float4*)(mcont + (size_t)C0 * 64);
    #pragma unroll
    for (int t = tid; t < ROWS * 16; t += 256) {
        int r = t >> 4, c4 = t & 15;
        *(float4*)&s_mc[r * PITCH + c4 * 4] = g_mc[t];
    }
    const float4* g_qp = (const float4*)(ws + WS_QP);
    const float4* g_qn = (const float4*)(ws + WS_QN);
    #pragma unroll
    for (int t = tid; t < NB * 16; t += 256) {
        int r = t >> 4, c4 = t & 15;
        *(float4*)&s_qp[r * PITCH + c4 * 4] = g_qp[t];
        *(float4*)&s_qn[r * PITCH + c4 * 4] = g_qn[t];
    }
    {   // mctx norms: thread t -> row r=t>>2, quarter q=t&3 (coalesced b128 loads)
        const int r = tid >> 2, q = tid & 3;
        const float* xr = mctx + (size_t)(C0 + r) * 64 + q * 16;
        float ss = 0.f;
        #pragma unroll
        for (int i = 0; i < 4; ++i) {
            float4 x = *(const float4*)&xr[i * 4];
            ss = fmaf(x.x, x.x, ss); ss = fmaf(x.y, x.y, ss);
            ss = fmaf(x.z, x.z, ss); ss = fmaf(x.w, x.w, ss);
        }
        ss += __shfl_xor(ss, 1, 64);
        ss += __shfl_xor(ss, 2, 64);
        if (q == 0) {
            s_inv[r]  = 0.3f / fmaxf(sqrtf(ss), CEPS);
            s_base[r] = 0.2f * fresh[C0 + r];
        }
    }
    __syncthreads();

    // ---- phase A: m_part = MC @ W1lo, 4c x 4j register tile.
    //      mc rows from LDS (stride 68 -> 2-way, free); W1 from global (broadcast, L1-hot)
    const int c_lo = tid & 15;
    const int j0 = (tid >> 4) * 4;
    {
        float acc[4][4] = {{0.f}};
        #pragma unroll 4
        for (int i4 = 0; i4 < 16; ++i4) {
            float4 w0 = *(const float4*)&W1[(64 + i4 * 4 + 0) * 64 + j0];
            float4 w1r = *(const float4*)&W1[(64 + i4 * 4 + 1) * 64 + j0];
            float4 w2r = *(const float4*)&W1[(64 + i4 * 4 + 2) * 64 + j0];
            float4 w3r = *(const float4*)&W1[(64 + i4 * 4 + 3) * 64 + j0];
            #pragma unroll
            for (int ci = 0; ci < 4; ++ci) {
                float4 m = *(const float4*)&s_mc[(c_lo + 16 * ci) * PITCH + i4 * 4];
                acc[ci][0] = fmaf(m.x, w0.x, acc[ci][0]);
                acc[ci][1] = fmaf(m.x, w0.y, acc[ci][1]);
                acc[ci][2] = fmaf(m.x, w0.z, acc[ci][2]);
                acc[ci][3] = fmaf(m.x, w0.w, acc[ci][3]);
                acc[ci][0] = fmaf(m.y, w1r.x, acc[ci][0]);
                acc[ci][1] = fmaf(m.y, w1r.y, acc[ci][1]);
                acc[ci][2] = fmaf(m.y, w1r.z, acc[ci][2]);
                acc[ci][3] = fmaf(m.y, w1r.w, acc[ci][3]);
                acc[ci][0] = fmaf(m.z, w2r.x, acc[ci][0]);
                acc[ci][1] = fmaf(m.z, w2r.y, acc[ci][1]);
                acc[ci][2] = fmaf(m.z, w2r.z, acc[ci][2]);
                acc[ci][3] = fmaf(m.z, w2r.w, acc[ci][3]);
                acc[ci][0] = fmaf(m.w, w3r.x, acc[ci][0]);
                acc[ci][1] = fmaf(m.w, w3r.y, acc[ci][1]);
                acc[ci][2] = fmaf(m.w, w3r.z, acc[ci][2]);
                acc[ci][3] = fmaf(m.w, w3r.w, acc[ci][3]);
            }
        }
        __syncthreads();   // all s_mc reads done; now overlay with m_part^T
        #pragma unroll
        for (int jj = 0; jj < 4; ++jj)
            #pragma unroll
            for (int ci = 0; ci < 4; ++ci)
                s_mc[(j0 + jj) * PITCH + c_lo + 16 * ci] = acc[ci][jj];  // 2-way, free
    }
    __syncthreads();

    // ---- phase B: 2b x 4c per thread; a1 c-vectorized via m_part^T float4 ----
    const int bq = (tid & 15) << 1;
    const int cq = (tid >> 4) << 2;
    float4 a1v[2];
    a1v[0] = make_float4(0.f, 0.f, 0.f, 0.f);
    a1v[1] = make_float4(0.f, 0.f, 0.f, 0.f);
    float a2[2][4] = {{0.f}};
    const float* mxb = mctx + (size_t)C0 * 64;

    #pragma unroll 4
    for (int j4 = 0; j4 < 16; ++j4) {
        const int jo = j4 * 4;
        float4 w2v = *(const float4*)(W2 + jo);                       // uniform -> s_load
        float4 qp0 = *(const float4*)&s_qp[ bq      * PITCH + jo];
        float4 qp1 = *(const float4*)&s_qp[(bq + 1) * PITCH + jo];
        float4 qn0 = *(const float4*)&s_qn[ bq      * PITCH + jo];
        float4 qn1 = *(const float4*)&s_qn[(bq + 1) * PITCH + jo];
        float4 m0 = *(const float4*)&s_mc[(jo + 0) * PITCH + cq];     // float4 over c
        float4 m1 = *(const float4*)&s_mc[(jo + 1) * PITCH + cq];
        float4 m2 = *(const float4*)&s_mc[(jo + 2) * PITCH + cq];
        float4 m3 = *(const float4*)&s_mc[(jo + 3) * PITCH + cq];

        #pragma unroll
        for (int bi = 0; bi < 2; ++bi) {
            float4 qp = bi ? qp1 : qp0;
            float4& av = a1v[bi];
            av.x = fmaf(fmaxf(qp.x + m0.x, 0.f), w2v.x, av.x);
            av.y = fmaf(fmaxf(qp.x + m0.y, 0.f), w2v.x, av.y);
            av.z = fmaf(fmaxf(qp.x + m0.z, 0.f), w2v.x, av.z);
            av.w = fmaf(fmaxf(qp.x + m0.w, 0.f), w2v.x, av.w);
            av.x = fmaf(fmaxf(qp.y + m1.x, 0.f), w2v.y, av.x);
            av.y = fmaf(fmaxf(qp.y + m1.y, 0.f), w2v.y, av.y);
            av.z = fmaf(fmaxf(qp.y + m1.z, 0.f), w2v.y, av.z);
            av.w = fmaf(fmaxf(qp.y + m1.w, 0.f), w2v.y, av.w);
            av.x = fmaf(fmaxf(qp.z + m2.x, 0.f), w2v.z, av.x);
            av.y = fmaf(fmaxf(qp.z + m2.y, 0.f), w2v.z, av.y);
            av.z = fmaf(fmaxf(qp.z + m2.z, 0.f), w2v.z, av.z);
            av.w = fmaf(fmaxf(qp.z + m2.w, 0.f), w2v.z, av.w);
            av.x = fmaf(fmaxf(qp.w + m3.x, 0.f), w2v.w, av.x);
            av.y = fmaf(fmaxf(qp.w + m3.y, 0.f), w2v.w, av.y);
            av.z = fmaf(fmaxf(qp.w + m3.z, 0.f), w2v.w, av.z);
            av.w = fmaf(fmaxf(qp.w + m3.w, 0.f), w2v.w, av.w);
        }
        #pragma unroll
        for (int ci = 0; ci < 4; ++ci) {
            float4 xv = *(const float4*)&mxb[(cq + ci) * 64 + jo];    // L1-hot
            a2[0][ci] = fmaf(qn0.x, xv.x, a2[0][ci]);
            a2[0][ci] = fmaf(qn0.y, xv.y, a2[0][ci]);
            a2[0][ci] = fmaf(qn0.z, xv.z, a2[0][ci]);
            a2[0][ci] = fmaf(qn0.w, xv.w, a2[0][ci]);
            a2[1][ci] = fmaf(qn1.x, xv.x, a2[1][ci]);
            a2[1][ci] = fmaf(qn1.y, xv.y, a2[1][ci]);
            a2[1][ci] = fmaf(qn1.z, xv.z, a2[1][ci]);
            a2[1][ci] = fmaf(qn1.w, xv.w, a2[1][ci]);
        }
    }

    // ---- epilogue: dense float4 stores, 2 per thread ----
    const float b2v = b2[0];
    float4 inv4  = *(const float4*)&s_inv[cq];
    float4 base4 = *(const float4*)&s_base[cq];
    #pragma unroll
    for (int bi = 0; bi < 2; ++bi) {
        float4 r;
        r.x = 0.5f / (1.f + expf(-(a1v[bi].x + b2v))) + a2[bi][0] * inv4.x + base4.x;
        r.y = 0.5f / (1.f + expf(-(a1v[bi].y + b2v))) + a2[bi][1] * inv4.y + base4.y;
        r.z = 0.5f / (1.f + expf(-(a1v[bi].z + b2v))) + a2[bi][2] * inv4.z + base4.z;
        r.w = 0.5f / (1.f + expf(-(a1v[bi].w + b2v))) + a2[bi][3] * inv4.w + base4.w;
        *(float4*)&ws[WS_FINAL + (size_t)(bq + bi) * CAP + C0 + cq] = r;
    }
}

// Bitonic sort of 64 (val,idx) pairs across a wave, descending by
// (val >, tie: idx <) -- the exact jax.lax.top_k total order.
// After: lane i holds the i-th best pair.  [proven construct, round 3]
__device__ __forceinline__ void bitonic64_desc(float& v, int& iv, int lane)
{
    #pragma unroll
    for (int k = 2; k <= 64; k <<= 1) {
        #pragma unroll
        for (int j = k >> 1; j > 0; j >>= 1) {
            float ov = __shfl_xor(v, j, 64);
            int   oi = __shfl_xor(iv, j, 64);
            bool low        = (lane & j) == 0;
            bool dirDesc    = (lane & k) == 0;
            bool takeBetter = (low == dirDesc);
            bool otherBetter = (ov > v) || (ov == v && oi < iv);
            if (otherBetter == takeBetter) { v = ov; iv = oi; }
        }
    }
}

// ---- top-k stage 1: one block (4 waves) per (row, 1024-chunk).
//      Wave owns 256 elems (4 regs/lane). 4 independent per-slice bitonic
//      sorts (ILP); wave top-16 is contained in the union of slice top-16s
//      (exact: a global-top element is top-16 within its own slice);
//      gather the 64 survivors one-per-lane; one bitonic sort -> wave
//      top-16; wave 0 merges 4x16 with a final bitonic sort.
__global__ __launch_bounds__(256) void topk_stage1(float* __restrict__ ws)
{
    __shared__ float s_val[64];
    __shared__ int   s_idx[64];

    const int lane = threadIdx.x & 63;
    const int w    = threadIdx.x >> 6;     // 0..3, subchunk id
    const int b    = blockIdx.y;
    float* row = ws + WS_FINAL + (size_t)b * CAP;
    const int cbase = blockIdx.x * CHUNK;
    const int sb = cbase + w * 256;

    // one float4 per lane; slice s = component s across the wave
    float4 t = *(const float4*)&row[sb + lane * 4];
    float v0 = t.x, v1 = t.y, v2 = t.z, v3 = t.w;
    int   i0 = sb + lane * 4 + 0;
    int   i1 = sb + lane * 4 + 1;
    int   i2 = sb + lane * 4 + 2;
    int   i3 = sb + lane * 4 + 3;

    // per-slice wave-wide sorts (independent -> ILP-overlapped)
    bitonic64_desc(v0, i0, lane);
    bitonic64_desc(v1, i1, lane);
    bitonic64_desc(v2, i2, lane);
    bitonic64_desc(v3, i3, lane);

    // gather: lane l takes rank (l&15) of slice (l>>4)
    const int r = lane & 15;
    float c0 = __shfl(v0, r, 64), c1 = __shfl(v1, r, 64);
    float c2 = __shfl(v2, r, 64), c3 = __shfl(v3, r, 64);
    int   d0 = __shfl(i0, r, 64), d1 = __shfl(i1, r, 64);
    int   d2 = __shfl(i2, r, 64), d3 = __shfl(i3, r, 64);
    const int s = lane >> 4;
    float cv = (s == 0) ? c0 : (s == 1) ? c1 : (s == 2) ? c2 : c3;
    int   ci = (s == 0) ? d0 : (s == 1) ? d1 : (s == 2) ? d2 : d3;

    bitonic64_desc(cv, ci, lane);          // lanes 0..15 = wave top-16 sorted

    if (lane < TOPK) {
        s_val[w * TOPK + lane] = cv;
        s_idx[w * TOPK + lane] = ci;
    }
    __syncthreads();
    if (w != 0) return;

    float mv = s_val[lane];
    int   mi = s_idx[lane];
    bitonic64_desc(mv, mi, lane);          // chunk top-16 sorted
    if (lane < TOPK) {
        row[cbase + lane]        = mv;
        row[cbase + TOPK + lane] = __int_as_float(mi);
    }
}

// ---- top-k stage 2: one block (8 waves) per row. 512 candidates ->
//      8 waves sort 64 each (top-16 kept, 128 survive) -> 2 waves sort
//      64 each (32 survive) -> wave 0 sorts 32 + sentinels -> final 16
//      sorted + fused gather. All bitonic64; all barriers block-wide.
__global__ __launch_bounds__(512) void topk_stage2(
    const float* __restrict__ mcont,
    const float* __restrict__ fresh,
    const float* __restrict__ ws,
    float* __restrict__ out)
{
    __shared__ float s_v1[128];
    __shared__ int   s_i1[128];
    __shared__ float s_v2[32];
    __shared__ int   s_i2[32];

    const int lane = threadIdx.x & 63;
    const int w    = threadIdx.x >> 6;     // 0..7
    const int b    = blockIdx.x;
    const float* row = ws + WS_FINAL + (size_t)b * CAP;

    // level 1: wave w sorts candidates [w*64, w*64+64)
    {
        const int cand = w * 64 + lane;
        const int ch = cand >> 4, pos = cand & 15;
        float v  = row[ch * CHUNK + pos];
        int   iv = __float_as_int(row[ch * CHUNK + TOPK + pos]);
        bitonic64_desc(v, iv, lane);
        if (lane < TOPK) {
            s_v1[w * TOPK + lane] = v;
            s_i1[w * TOPK + lane] = iv;
        }
    }
    __syncthreads();

    // level 2: waves 0..1 sort 64 of the 128 survivors
    if (w < 2) {
        float v  = s_v1[w * 64 + lane];
        int   iv = s_i1[w * 64 + lane];
        bitonic64_desc(v, iv, lane);
        if (lane < TOPK) {
            s_v2[w * TOPK + lane] = v;
            s_i2[w * TOPK + lane] = iv;
        }
    }
    __syncthreads();
    if (w != 0) return;

    // level 3: 32 survivors + 32 sentinels -> final sorted top-16
    float fv = (lane < 32) ? s_v2[lane] : -INFINITY;
    int   fi = (lane < 32) ? s_i2[lane] : 0x7FFFFFFF;
    bitonic64_desc(fv, fi, lane);

    float* out_content = out;                       // [32][16][64]
    float* out_sim     = out + NB * TOPK * 64;      // [32][16]
    float* out_tw      = out + NB * TOPK * 64 + NB * TOPK;

    if (lane < TOPK) {
        out_sim[b * TOPK + lane] = fv;
        out_tw [b * TOPK + lane] = fresh[fi];
    }

    #pragma unroll
    for (int r = 0; r < TOPK; ++r) {
        int wi = __shfl(fi, r, 64);
        out_content[(size_t)b * TOPK * 64 + r * 64 + lane] =
            mcont[(size_t)wi * 64 + lane];
    }
}

extern "C" void kernel_launch(void* const* d_in, const int* in_sizes, int n_in,
                              void* d_out, int out_size, void* d_ws, size_t ws_size,
                              hipStream_t stream) {
    const float* qc    = (const float*)d_in[0];
    const float* qctx  = (const float*)d_in[1];
    const float* mcont = (const float*)d_in[2];
    const float* mctx  = (const float*)d_in[3];
    const float* fresh = (const float*)d_in[4];
    const float* W1    = (const float*)d_in[5];
    const float* b1    = (const float*)d_in[6];
    const float* W2    = (const float*)d_in[7];
    const float* b2    = (const float*)d_in[8];
    float* out = (float*)d_out;
    float* ws  = (float*)d_ws;

    prep_kernel<<<NB, 64, 0, stream>>>(qc, qctx, W1, b1, ws);
    score_kernel<<<NBLK, 256, 0, stream>>>(mcont, mctx, fresh, W1, W2, b2, ws);
    topk_stage1<<<dim3(NCHUNK, NB), 256, 0, stream>>>(ws);
    topk_stage2<<<NB, 512, 0, stream>>>(mcont, fresh, ws, out);
}